// Round 9
// baseline (182.998 us; speedup 1.0000x reference)
//
#include <hip/hip_runtime.h>

#define L_SEQ 2048
#define DM    1024
#define NH    16
#define DH    64
#define BLM   4096   // B * L

typedef __bf16 bf16x8 __attribute__((ext_vector_type(8)));
typedef __bf16 bf16x4 __attribute__((ext_vector_type(4)));
typedef short  s16x4  __attribute__((ext_vector_type(4)));
typedef float  f32x4  __attribute__((ext_vector_type(4)));

#define MFMA(a,b,c) __builtin_amdgcn_mfma_f32_16x16x32_bf16(a,b,c,0,0,0)

// 16x16x16 bf16 MFMA (K=16, A/B = 4 bf16 = 2 VGPRs) — builtin name hedge
__device__ __forceinline__ f32x4 mfma16(bf16x4 a, bf16x4 b, f32x4 c) {
#if __has_builtin(__builtin_amdgcn_mfma_f32_16x16x16_bf16)
    return __builtin_amdgcn_mfma_f32_16x16x16_bf16(a, b, c, 0, 0, 0);
#elif __has_builtin(__builtin_amdgcn_mfma_f32_16x16x16bf16_1k)
    return __builtin_amdgcn_mfma_f32_16x16x16bf16_1k(
        __builtin_bit_cast(s16x4, a), __builtin_bit_cast(s16x4, b), c, 0, 0, 0);
#else
    asm("v_mfma_f32_16x16x16_bf16 %0, %1, %2, %3" : "=&v"(c) : "v"(a), "v"(b), "0"(c));
    return c;
#endif
}

__device__ __forceinline__ unsigned short f2b(float x) {
    unsigned int u = __builtin_bit_cast(unsigned int, x);
    u = (u + 0x7fffu + ((u >> 16) & 1u)) >> 16;   // RNE, inputs finite
    return (unsigned short)u;
}

typedef __attribute__((address_space(1))) unsigned int GU32;
typedef __attribute__((address_space(3))) unsigned int LU32;
__device__ __forceinline__ void async16(const void* g, void* l) {
    __builtin_amdgcn_global_load_lds((GU32*)g, (LU32*)l, 16, 0, 0);
}

// ---------------- conversion: f32 -> bf16, 8 elems/thread ----------------
__global__ __launch_bounds__(256) void conv_x(const float* __restrict__ in,
                                              unsigned short* __restrict__ out, int n8) {
    int i = blockIdx.x * 256 + threadIdx.x;
    if (i >= n8) return;
    float4 a = ((const float4*)in)[i * 2];
    float4 b = ((const float4*)in)[i * 2 + 1];
    uint4 v;
    v.x = (unsigned)f2b(a.x) | ((unsigned)f2b(a.y) << 16);
    v.y = (unsigned)f2b(a.z) | ((unsigned)f2b(a.w) << 16);
    v.z = (unsigned)f2b(b.x) | ((unsigned)f2b(b.y) << 16);
    v.w = (unsigned)f2b(b.z) | ((unsigned)f2b(b.w) << 16);
    ((uint4*)out)[i] = v;
}

// -------- transpose + convert: W[k][coff+n] (f32, row stride ld) -> out[n][k] bf16 -----
__global__ __launch_bounds__(256) void transpose_w(const float* __restrict__ W, int ld, int coff,
                                                   unsigned short* __restrict__ out) {
    __shared__ float t[32][33];
    int k0 = blockIdx.x * 32, n0 = blockIdx.y * 32;
    int tx = threadIdx.x & 31, ty = threadIdx.x >> 5;   // ty 0..7
    #pragma unroll
    for (int i = 0; i < 4; i++) {
        int k = k0 + ty + i * 8;
        t[ty + i * 8][tx] = W[(size_t)k * ld + coff + n0 + tx];
    }
    __syncthreads();
    #pragma unroll
    for (int i = 0; i < 4; i++) {
        int n = n0 + ty + i * 8;
        out[(size_t)n * DM + k0 + tx] = f2b(t[tx][ty + i * 8]);
    }
}

// -------- K [4096][1024] bf16 -> K_T [(b*16+h)*64 + d][2048] bf16 ----------
// Keys PERMUTED within each 64-tile: pos(key: nt*16+lg*4+r) = lg*16+nt*4+r,
// so attn PV B-fragments (16x16x16) read contiguously.
__global__ __launch_bounds__(256) void transpose_k(const unsigned short* __restrict__ kb,
                                                   unsigned short* __restrict__ kt) {
    __shared__ unsigned short t[64][66];
    int l0 = blockIdx.x * 64;
    int bh = blockIdx.y;                 // 0..31
    int b = bh >> 4, h = bh & 15;
    int c = threadIdx.x & 63, r4 = threadIdx.x >> 6;  // c: inner coord, r4: 0..3
    #pragma unroll
    for (int i = 0; i < 16; i++) {
        int l = r4 + i * 4;
        t[l][c] = kb[(size_t)(b * L_SEQ + l0 + l) * DM + h * DH + c];
    }
    __syncthreads();
    const int cp = ((c >> 2) & 3) * 16 + ((c >> 4) << 2) + (c & 3);   // pi(c)
    #pragma unroll
    for (int i = 0; i < 16; i++) {
        int d = r4 + i * 4;
        kt[(size_t)(bh * DH + d) * L_SEQ + l0 + cp] = t[c][d];
    }
}

// ---------------- GEMM: C[M=4096][N=1024] = A @ BT^T + bias ----------------
// tile 128x64, BK=64, 4 waves (2x2, per-wave 64x32, acc 4x2: 12 b128 -> 16
// MFMA per iter); 512 blocks = 2/CU; 3-buffer staging (72KB), counted
// vmcnt(6) (vmcnt(0) final); XOR-swizzled LDS; bijective XCD swizzle 8*64.
template <int OUT_BF16>
__global__ __launch_bounds__(256) void gemm_bt(const unsigned short* __restrict__ A,
                                               const unsigned short* __restrict__ BT,
                                               const float* __restrict__ bias,
                                               void* __restrict__ Cv) {
    __shared__ __align__(16) unsigned short lA[3][128 * 64];   // 16KB each
    __shared__ __align__(16) unsigned short lB[3][64 * 64];    // 8KB each
    const int old = blockIdx.x + (blockIdx.y << 5);      // grid (32,16) -> 0..511
    const int nl = (old & 7) * 64 + (old >> 3);          // bijective, 512 = 8*64
    const int bm = nl >> 4, bn = nl & 15;                // bm 0..31, bn 0..15
    const int tid = threadIdx.x, wid = tid >> 6, lane = tid & 63;
    const int wr = wid >> 1, wc = wid & 1;
    const int lg = lane >> 4, lc = lane & 15;
    const int sr8 = lane >> 3;                           // row-in-8-group
    const int sc = (lane & 7) ^ sr8;                     // pre-swizzled source chunk

    f32x4 acc[4][2];
    #pragma unroll
    for (int m = 0; m < 4; m++)
        #pragma unroll
        for (int n = 0; n < 2; n++) acc[m][n] = (f32x4){0.f, 0.f, 0.f, 0.f};

    const unsigned short* gA = A + (size_t)bm * 128 * DM;
    const unsigned short* gB = BT + (size_t)bn * 64 * DM;

#define GSTAGE(buf, kk) do { \
    _Pragma("unroll") \
    for (int i = 0; i < 4; i++) \
        async16(gA + (size_t)(wid * 32 + i * 8 + sr8) * DM + (kk) + sc * 8, \
                lA[buf] + (wid * 32 + i * 8) * 64 + lane * 8); \
    _Pragma("unroll") \
    for (int i = 0; i < 2; i++) \
        async16(gB + (size_t)(wid * 16 + i * 8 + sr8) * DM + (kk) + sc * 8, \
                lB[buf] + (wid * 16 + i * 8) * 64 + lane * 8); \
} while (0)

    GSTAGE(0, 0);
    GSTAGE(1, 64);
    int cur = 0, pre = 2;
    const int NT = DM / 64;   // 16
    for (int t = 0; t < NT; ++t) {
        if (t + 1 < NT) asm volatile("s_waitcnt vmcnt(6)\n\ts_barrier" ::: "memory");
        else            asm volatile("s_waitcnt vmcnt(0)\n\ts_barrier" ::: "memory");
        if (t + 2 < NT) GSTAGE(pre, (t + 2) * 64);

        #pragma unroll
        for (int ks = 0; ks < 2; ks++) {
            bf16x8 af[4], bfv[2];
            #pragma unroll
            for (int m = 0; m < 4; m++) {
                int row = wr * 64 + m * 16 + lc;
                af[m] = *(const bf16x8*)(lA[cur] + row * 64 + ((ks * 4 + lg) ^ (lc & 7)) * 8);
            }
            #pragma unroll
            for (int n = 0; n < 2; n++) {
                int row = wc * 32 + n * 16 + lc;
                bfv[n] = *(const bf16x8*)(lB[cur] + row * 64 + ((ks * 4 + lg) ^ (lc & 7)) * 8);
            }
            #pragma unroll
            for (int m = 0; m < 4; m++)
                #pragma unroll
                for (int n = 0; n < 2; n++)
                    acc[m][n] = MFMA(af[m], bfv[n], acc[m][n]);
        }

        cur = (cur == 2) ? 0 : cur + 1;
        pre = (pre == 2) ? 0 : pre + 1;
    }
#undef GSTAGE

    #pragma unroll
    for (int m = 0; m < 4; m++) {
        int grow = bm * 128 + wr * 64 + m * 16 + lg * 4;
        #pragma unroll
        for (int n = 0; n < 2; n++) {
            int gcol = bn * 64 + wc * 32 + n * 16 + lc;
            float bs = bias[gcol];
            #pragma unroll
            for (int r = 0; r < 4; r++) {
                float v = acc[m][n][r] + bs;
                if (OUT_BF16)
                    ((unsigned short*)Cv)[(size_t)(grow + r) * DM + gcol] = f2b(v);
                else
                    ((float*)Cv)[(size_t)(grow + r) * DM + gcol] = v;
            }
        }
    }
}

// ---------------- flash attention over Kh (Q=K=V=Kh) ----------------
// 4 waves/block, EACH WAVE OWNS 32 q-rows (two Q fragment sets share one set
// of K/V LDS reads — per-q LDS cost halved vs R8). Swapped QK^T + in-register
// PV (16x16x16). Fixed softmax offset 16. 3-buffer staging, counted vmcnt(4);
// XOR-swizzled LDS; bijective XCD swizzle.
__global__ __launch_bounds__(256) void attn_kernel(const unsigned short* __restrict__ kb,
                                                   const unsigned short* __restrict__ kt,
                                                   unsigned short* __restrict__ ob) {
    const int lin = blockIdx.x + (blockIdx.y << 4) + (blockIdx.z << 8);
    const int nl = (lin & 7) * 64 + (lin >> 3);          // bijective, 512 = 8*64
    const int qblk = nl & 15, h = (nl >> 4) & 15, b = nl >> 8;
    const int tid = threadIdx.x, wid = tid >> 6, lane = tid & 63;
    const int lg = lane >> 4, lc = lane & 15;
    const int q0 = qblk * 128 + wid * 32;
    const int bh = b * NH + h;

    __shared__ __align__(16) unsigned short kT[3][64 * 64];   // [key][d]
    __shared__ __align__(16) unsigned short vT[3][64 * 64];   // [d][key-permuted]

    const int sr8 = lane >> 3;
    const int sc = (lane & 7) ^ sr8;
    const unsigned short* gK = kb + (size_t)b * L_SEQ * DM + h * DH;
    const unsigned short* gV = kt + (size_t)bh * DH * L_SEQ;

#define ASTAGE(buf, k0n) do { \
    _Pragma("unroll") \
    for (int i = 0; i < 2; i++) { \
        int rr = wid * 16 + i * 8 + sr8; \
        async16(gK + (size_t)((k0n) + rr) * DM + sc * 8, kT[buf] + (wid * 16 + i * 8) * 64 + lane * 8); \
        async16(gV + (size_t)rr * L_SEQ + (k0n) + sc * 8, vT[buf] + (wid * 16 + i * 8) * 64 + lane * 8); \
    } \
} while (0)

    // two Q fragment sets: rows q0+lc and q0+16+lc
    bf16x8 a_q0[2], a_q1[2];
    {
        const unsigned short* base = kb + (size_t)(b * L_SEQ + q0 + lc) * DM + h * DH;
        a_q0[0] = *(const bf16x8*)(base + lg * 8);
        a_q0[1] = *(const bf16x8*)(base + 32 + lg * 8);
        const unsigned short* base2 = base + (size_t)16 * DM;
        a_q1[0] = *(const bf16x8*)(base2 + lg * 8);
        a_q1[1] = *(const bf16x8*)(base2 + 32 + lg * 8);
    }

    bf16x4 ones4;
    #pragma unroll
    for (int i = 0; i < 4; i++) ones4[i] = (__bf16)1.0f;

    f32x4 l_lo = (f32x4){0.f, 0.f, 0.f, 0.f}, l_hi = l_lo;
    f32x4 o_lo[4], o_hi[4];
    #pragma unroll
    for (int dt = 0; dt < 4; dt++) { o_lo[dt] = l_lo; o_hi[dt] = l_lo; }

    const int NT = L_SEQ / 64;   // 32
    ASTAGE(0, 0);
    ASTAGE(1, 64);

    int cur = 0, pre = 2;
    for (int t = 0; t < NT; ++t) {
        if (t + 1 < NT) asm volatile("s_waitcnt vmcnt(4)\n\ts_barrier" ::: "memory");
        else            asm volatile("s_waitcnt vmcnt(0)\n\ts_barrier" ::: "memory");
        if (t + 2 < NT) ASTAGE(pre, (t + 2) * 64);

        // S^T = K . Q^T for both q-subtiles, sharing K fragments
        f32x4 sl[4], sh[4];
        #pragma unroll
        for (int nt = 0; nt < 4; nt++) {
            const int r = nt * 16 + lc, x = lc & 7;
            const unsigned short* kbase = &kT[cur][r * 64];
            bf16x8 k0v = *(const bf16x8*)(kbase + ((lg    ) ^ x) * 8);
            bf16x8 k1v = *(const bf16x8*)(kbase + ((lg + 4) ^ x) * 8);
            f32x4 a = (f32x4){0.f, 0.f, 0.f, 0.f};
            a = MFMA(k0v, a_q0[0], a);
            sl[nt] = MFMA(k1v, a_q0[1], a);
            f32x4 a2 = (f32x4){0.f, 0.f, 0.f, 0.f};
            a2 = MFMA(k0v, a_q1[0], a2);
            sh[nt] = MFMA(k1v, a_q1[1], a2);
        }

        // P = exp(s*0.125 - 16) -> bf16 A-fragments (fixed offset, see R7 notes)
        bf16x4 pl[4], ph[4];
        #pragma unroll
        for (int nt = 0; nt < 4; nt++)
            #pragma unroll
            for (int r = 0; r < 4; r++) {
                pl[nt][r] = (__bf16)__expf(__builtin_fmaf(sl[nt][r], 0.125f, -16.0f));
                ph[nt][r] = (__bf16)__expf(__builtin_fmaf(sh[nt][r], 0.125f, -16.0f));
            }

        // row-sums via ones-MFMA
        #pragma unroll
        for (int nt = 0; nt < 4; nt++) {
            l_lo = mfma16(pl[nt], ones4, l_lo);
            l_hi = mfma16(ph[nt], ones4, l_hi);
        }

        // PV: V fragments read once, used by both q-subtiles
        #pragma unroll
        for (int dt = 0; dt < 4; dt++) {
            const int row = dt * 16 + lc, x = lc & 7;
            const unsigned short* vbase = &vT[cur][row * 64];
            #pragma unroll
            for (int hh = 0; hh < 2; hh++) {
                bf16x8 vb = *(const bf16x8*)(vbase + ((lg * 2 + hh) ^ x) * 8);
                bf16x4 vlo = __builtin_shufflevector(vb, vb, 0, 1, 2, 3);
                bf16x4 vhi = __builtin_shufflevector(vb, vb, 4, 5, 6, 7);
                o_lo[dt] = mfma16(pl[hh * 2],     vlo, o_lo[dt]);
                o_lo[dt] = mfma16(pl[hh * 2 + 1], vhi, o_lo[dt]);
                o_hi[dt] = mfma16(ph[hh * 2],     vlo, o_hi[dt]);
                o_hi[dt] = mfma16(ph[hh * 2 + 1], vhi, o_hi[dt]);
            }
        }

        cur = (cur == 2) ? 0 : cur + 1;
        pre = (pre == 2) ? 0 : pre + 1;
    }
#undef ASTAGE

    #pragma unroll
    for (int r = 0; r < 4; r++) {
        float inv_lo = 1.0f / l_lo[r];
        float inv_hi = 1.0f / l_hi[r];
        int row_lo = q0 + lg * 4 + r;
        unsigned short* orow_lo = ob + (size_t)(b * L_SEQ + row_lo) * DM + h * DH;
        unsigned short* orow_hi = orow_lo + (size_t)16 * DM;
        #pragma unroll
        for (int dt = 0; dt < 4; dt++) {
            orow_lo[dt * 16 + lc] = f2b(o_lo[dt][r] * inv_lo);
            orow_hi[dt * 16 + lc] = f2b(o_hi[dt][r] * inv_hi);
        }
    }
}

extern "C" void kernel_launch(void* const* d_in, const int* in_sizes, int n_in,
                              void* d_out, int out_size, void* d_ws, size_t ws_size,
                              hipStream_t stream) {
    (void)in_sizes; (void)n_in; (void)out_size;
    const float* x      = (const float*)d_in[0];
    const float* W_attn = (const float*)d_in[1];
    const float* b_attn = (const float*)d_in[2];
    const float* W_proj = (const float*)d_in[3];
    const float* b_proj = (const float*)d_in[4];
    float* out = (float*)d_out;

    char* ws = (char*)d_ws;
    const size_t SZ_XB = (size_t)BLM * DM * 2;    // 8 MiB
    const size_t SZ_W  = (size_t)DM * DM * 2;     // 2 MiB
    unsigned short* xb  = (unsigned short*)(ws);
    unsigned short* wkT = (unsigned short*)(ws + SZ_XB);
    unsigned short* wpT = (unsigned short*)(ws + SZ_XB + SZ_W);
    unsigned short* kbf = (unsigned short*)(ws + SZ_XB + 2 * SZ_W);
    unsigned short* ktr = (unsigned short*)(ws + 2 * SZ_XB + 2 * SZ_W);
    unsigned short* obf = (unsigned short*)(ws + 3 * SZ_XB + 2 * SZ_W);
    if (ws_size < 4 * SZ_XB + 2 * SZ_W) return;   // need ~38 MB scratch

    conv_x<<<dim3(BLM * DM / 8 / 256), dim3(256), 0, stream>>>(x, xb, BLM * DM / 8);
    transpose_w<<<dim3(32, 32), dim3(256), 0, stream>>>(W_attn, 3 * DM, DM, wkT);
    transpose_w<<<dim3(32, 32), dim3(256), 0, stream>>>(W_proj, DM, 0, wpT);
    gemm_bt<1><<<dim3(32, 16), dim3(256), 0, stream>>>(xb, wkT, b_attn + DM, (void*)kbf);
    transpose_k<<<dim3(L_SEQ / 64, 32), dim3(256), 0, stream>>>(kbf, ktr);
    attn_kernel<<<dim3(16, 16, 2), dim3(256), 0, stream>>>(kbf, ktr, obf);
    gemm_bt<0><<<dim3(32, 16), dim3(256), 0, stream>>>(obf, wpT, b_proj, out);
}